// Round 9
// baseline (176.907 us; speedup 1.0000x reference)
//
#include <hip/hip_runtime.h>
#include <math.h>

// B=4 graphs, N=256 nodes (128+128)/graph, F=256, L=3 layers.
// 11 launches: prep + 3x{hqk, attn, lin} + fin (r5 shape — empirically best).
// Cost model: dur = C(~100us harness) + E + n*1.3us. Kernels must be WIDE
// (256 blocks) and SHALLOW (r7/r8 deep-phase merges regressed).
// qs/ks via qs = x.(W@q)  (wqk precomputed; row-local fp32 — r7-validated).
// GEMMs: bf16 MFMA 16x16x32, one wave per 16x16 tile, operands L2-resident.

typedef __attribute__((ext_vector_type(8))) short short8;   // 8 bf16
typedef __attribute__((ext_vector_type(4))) float f32x4;
typedef unsigned short u16;
typedef unsigned int   u32;

__device__ __forceinline__ u16 f2bf(float f) {
    union { float f; u32 u; } v; v.f = f;
    u32 r = v.u + 0x7fffu + ((v.u >> 16) & 1u);     // RNE
    return (u16)(r >> 16);
}
__device__ __forceinline__ short8 ld8(const u16* p) {
    return __builtin_bit_cast(short8, *(const int4*)p);
}

// ---- P0: pack x (fp32+bf16) + Wt transpose + lwb cast + wqk = W @ q/k ------
__global__ __launch_bounds__(256) void k_prep(
    const float* __restrict__ d0, const float* __restrict__ d1,
    const float* __restrict__ conv_w, const float* __restrict__ lin_w,
    const float* __restrict__ conv_q, const float* __restrict__ conv_k,
    float* __restrict__ x, u16* __restrict__ xb,
    u16* __restrict__ Wt, u16* __restrict__ lwb, float* __restrict__ wqk) {
    for (int i = blockIdx.x * 256 + threadIdx.x; i < 1051648; i += 262144) {
        if (i < 262144) {
            int node = i >> 8, f = i & 255, b = node >> 8, nl = node & 255;
            float v = (nl < 128) ? d0[b * 32768 + f * 128 + nl]
                                 : d1[b * 32768 + f * 128 + (nl - 128)];
            x[i] = v; xb[i] = f2bf(v);
        } else if (i < 655360) {
            int o = i - 262144;                     // 6 mats of 256x256
            int mat = o >> 16, rem = o & 65535, e = rem >> 8, f = rem & 255;
            Wt[o] = f2bf(conv_w[mat * 65536 + f * 256 + e]);
        } else if (i < 1048576) {
            int o = i - 655360;
            lwb[o] = f2bf(lin_w[o]);
        } else {
            int o = i - 1048576;                    // 0..3071
            int c2 = o >> 8;                        // layer*4 + rel*2 + qk
            int layer = c2 >> 2, rel = (c2 >> 1) & 1, qk = c2 & 1, f = o & 255;
            const float* vec  = (qk ? conv_k : conv_q) + layer * 256;
            const float* wrow = conv_w + (layer * 2 + rel) * 65536 + f * 256;
            float s = 0.f;
            #pragma unroll 4
            for (int e = 0; e < 256; e += 4) {
                float4 w4 = *(const float4*)&wrow[e];
                float4 v4 = *(const float4*)&vec[e];
                s += w4.x * v4.x + w4.y * v4.y + w4.z * v4.z + w4.w * v4.w;
            }
            wqk[layer * 1024 + (rel * 2 + qk) * 256 + f] = s;
        }
    }
}

// ---- K1: BN-apply(prev) + H-GEMM -> Ht + (eg==0) qkbuf dots ----------------
// grid 256 = (64 m-tiles) x (4 e-groups); 256 thr (4 waves).
__global__ __launch_bounds__(256, 1) void k_hqk(
    const float* __restrict__ xprev, const float* __restrict__ msg2,
    const float* __restrict__ sums, const float* __restrict__ sumsq, // [256][64]
    const float* __restrict__ bw, const float* __restrict__ bb,
    const u16* __restrict__ cwt,                 // [2][256 e][256 f]
    const float* __restrict__ wqk_l,             // [4][256]  combo=rel*2+qk
    float* __restrict__ xcur, u16* __restrict__ xb, u16* __restrict__ Ht,
    float* __restrict__ qkbuf,                   // [4][1024]
    int do_bn) {
    __shared__ __align__(16) u16 Asub[16 * 264];  // [16 nodes][256 f] bf16
    __shared__ __align__(16) float Xs[16][260];   // fp32 rows for qk dots
    const int tid = threadIdx.x;
    const int mt = blockIdx.x >> 2, eg = blockIdx.x & 3;
    const int m0 = mt * 16;
    const int lane = tid & 63, widx = tid >> 6;
    const int row = lane & 15, kg = lane >> 4;

    float scale = 0.f, shift = 0.f;
    if (do_bn) {                                  // col = tid, redundant/block
        float s1 = 0.f, s2 = 0.f;
        #pragma unroll
        for (int c = 0; c < 64; c += 4) {
            float4 a4 = *(const float4*)&sums[tid * 64 + c];
            float4 b4 = *(const float4*)&sumsq[tid * 64 + c];
            s1 += (a4.x + a4.y) + (a4.z + a4.w);
            s2 += (b4.x + b4.y) + (b4.z + b4.w);
        }
        float mu  = s1 * (1.f / 1024.f);
        float var = s2 * (1.f / 1024.f) - mu * mu;        // biased, as reference
        scale = bw[tid] * rsqrtf(var + 1e-5f);
        shift = bb[tid] - mu * scale;
    }
    #pragma unroll
    for (int r = 0; r < 16; ++r) {                // x_cur rows, col = tid
        int idx = (m0 + r) * 256 + tid;
        float v = xprev[idx];
        if (do_bn) v += msg2[idx] * scale + shift;
        u16 hb = f2bf(v);
        Asub[r * 264 + tid] = hb;
        Xs[r][tid] = v;
        if (do_bn && eg == 0) { xcur[idx] = v; xb[idx] = hb; }
    }
    __syncthreads();

    const int et = eg * 4 + widx, e0 = et * 16;   // e-tile 0..15
    const u16* B0 = cwt + (e0 + row) * 256 + kg * 8;
    const u16* B1 = B0 + 65536;
    const u16* Ap = &Asub[row * 264 + kg * 8];
    f32x4 acc0 = {0.f,0.f,0.f,0.f}, acc1 = {0.f,0.f,0.f,0.f};
    #pragma unroll
    for (int k0 = 0; k0 < 256; k0 += 32) {
        short8 a = ld8(Ap + k0);
        acc0 = __builtin_amdgcn_mfma_f32_16x16x32_bf16(a, ld8(B0 + k0), acc0, 0, 0, 0);
        acc1 = __builtin_amdgcn_mfma_f32_16x16x32_bf16(a, ld8(B1 + k0), acc1, 0, 0, 0);
    }
    // D: col(lane&15)=e, row(kg*4+c)=node -> store transposed Ht[r][e][node]
    ushort4 o0, o1;
    o0.x = f2bf(acc0[0]); o0.y = f2bf(acc0[1]); o0.z = f2bf(acc0[2]); o0.w = f2bf(acc0[3]);
    o1.x = f2bf(acc1[0]); o1.y = f2bf(acc1[1]); o1.z = f2bf(acc1[2]); o1.w = f2bf(acc1[3]);
    *(ushort4*)(Ht + (e0 + row) * 1024 + m0 + kg * 4) = o0;
    *(ushort4*)(Ht + 262144 + (e0 + row) * 1024 + m0 + kg * 4) = o1;

    // qk scores for this block's 16 rows (fp32 exact): wave widx -> combo widx
    if (eg == 0) {
        float4 w4 = *(const float4*)&wqk_l[widx * 256 + lane * 4];
        #pragma unroll
        for (int r = 0; r < 16; ++r) {
            float4 xv = *(const float4*)&Xs[r][lane * 4];
            float s = xv.x * w4.x + xv.y * w4.y + xv.z * w4.z + xv.w * w4.w;
            s += __shfl_xor(s, 32); s += __shfl_xor(s, 16); s += __shfl_xor(s, 8);
            s += __shfl_xor(s, 4);  s += __shfl_xor(s, 2);  s += __shfl_xor(s, 1);
            if (lane == 0) qkbuf[widx * 1024 + m0 + r] = s;
        }
    }
}

// ---- K2: alpha softmax + attn GEMM + relu/bias -> msg1b --------------------
// grid 256 = (64 dst-tiles) x (4 e-groups); 256 thr.
__global__ __launch_bounds__(256, 1) void k_attn(
    const float* __restrict__ qkbuf, const u16* __restrict__ Ht,
    const float* __restrict__ cb, u16* __restrict__ msg1b) {
    __shared__ __align__(16) u16 Atile[16 * 264]; // alpha bf16 [16 dst][256 src]
    __shared__ float ksl[2][256];
    __shared__ float qsl[2][16];
    __shared__ __align__(16) float T[4][16 * 20];
    const int tid = threadIdx.x;
    const int mt = blockIdx.x >> 2, eg = blockIdx.x & 3;
    const int m0 = mt * 16;
    const int g = mt >> 4, a = (mt >> 3) & 1;
    ksl[0][tid] = qkbuf[1 * 1024 + g * 256 + tid];   // combo rel*2+1 = k-score
    ksl[1][tid] = qkbuf[3 * 1024 + g * 256 + tid];
    if (tid < 32) {
        int rel = tid >> 4, r = tid & 15;
        qsl[rel][r] = qkbuf[(rel * 2) * 1024 + m0 + r];
    }
    __syncthreads();
    {   // softmax: thread = (dst r = tid>>4, src chunk j = tid&15)
        const int r = tid >> 4, j = tid & 15;
        const int dl = (m0 + r) & 255;
        const int s0 = j * 16;
        const int rel = ((s0 >> 7) == a) ? 0 : 1; // chunk never crosses 128
        float qv = qsl[rel][r];
        float l[16], mx = -1e30f;
        #pragma unroll
        for (int i2 = 0; i2 < 16; ++i2) {
            float v = qv + ksl[rel][s0 + i2];
            v = (v >= 0.f) ? v : 0.2f * v;        // leaky_relu 0.2
            if (s0 + i2 == dl) v = -1e30f;        // no self-loop
            l[i2] = v; mx = fmaxf(mx, v);
        }
        #pragma unroll
        for (int off = 1; off < 16; off <<= 1) mx = fmaxf(mx, __shfl_xor(mx, off));
        float s = 0.f;
        #pragma unroll
        for (int i2 = 0; i2 < 16; ++i2) { l[i2] = __expf(l[i2] - mx); s += l[i2]; }
        #pragma unroll
        for (int off = 1; off < 16; off <<= 1) s += __shfl_xor(s, off);
        float inv = 1.f / (s + 1e-16f);
        #pragma unroll
        for (int i2 = 0; i2 < 16; i2 += 2) {
            u32 p = (u32)f2bf(l[i2] * inv) | ((u32)f2bf(l[i2 + 1] * inv) << 16);
            *(u32*)&Atile[r * 264 + s0 + i2] = p;
        }
    }
    __syncthreads();
    const int lane = tid & 63, widx = tid >> 6;
    const int row = lane & 15, kg = lane >> 4;
    const int et = eg * 4 + widx, e0 = et * 16;
    const u16* Ap = &Atile[row * 264 + kg * 8];
    f32x4 acc = {0.f,0.f,0.f,0.f};
    #pragma unroll
    for (int k0 = 0; k0 < 256; k0 += 32) {
        const int rel = (((k0 >> 7) & 1) == a) ? 0 : 1;   // tile-uniform
        const u16* B = Ht + rel * 262144 + (e0 + row) * 1024 + g * 256 + k0 + kg * 8;
        acc = __builtin_amdgcn_mfma_f32_16x16x32_bf16(ld8(Ap + k0), ld8(B), acc, 0, 0, 0);
    }
    float bias = cb[e0 + row];
    float* Tw = &T[widx][0];
    #pragma unroll
    for (int c = 0; c < 4; ++c)
        Tw[(kg * 4 + c) * 20 + row] = fmaxf(acc[c] + bias, 0.f);
    __syncthreads();
    float4 v = *(float4*)&Tw[row * 20 + kg * 4];
    u32 lo = (u32)f2bf(v.x) | ((u32)f2bf(v.y) << 16);
    u32 hi = (u32)f2bf(v.z) | ((u32)f2bf(v.w) << 16);
    uint2 ov = {lo, hi};
    *(uint2*)(msg1b + (m0 + row) * 256 + eg * 64 + widx * 16 + kg * 4) = ov;
}

// ---- K3: lin GEMM (K=512) + BN partial stats (transposed layout) -----------
// grid 256 = (64 m-tiles) x (4 n-groups); 256 thr.
__global__ __launch_bounds__(256, 1) void k_lin(
    const u16* __restrict__ xb, const u16* __restrict__ msg1b,
    const u16* __restrict__ lwp, const float* __restrict__ lb,
    float* __restrict__ msg2, float* __restrict__ sums, float* __restrict__ sumsq) {
    __shared__ __align__(16) float T[4][16 * 20];
    const int tid = threadIdx.x, lane = tid & 63, widx = tid >> 6;
    const int row = lane & 15, kg = lane >> 4;
    const int mt = blockIdx.x >> 2, ng = blockIdx.x & 3;
    const int m0 = mt * 16;
    const int nt = ng * 4 + widx, n0 = nt * 16;
    const u16* A0 = xb    + (m0 + row) * 256 + kg * 8;
    const u16* A1 = msg1b + (m0 + row) * 256 + kg * 8;
    const u16* B  = lwp + (n0 + row) * 512 + kg * 8;
    f32x4 acc = {0.f,0.f,0.f,0.f};
    #pragma unroll
    for (int k0 = 0; k0 < 512; k0 += 32) {
        short8 av = (k0 < 256) ? ld8(A0 + k0) : ld8(A1 + (k0 - 256));
        acc = __builtin_amdgcn_mfma_f32_16x16x32_bf16(av, ld8(B + k0), acc, 0, 0, 0);
    }
    float bias = lb[n0 + row];
    float v0 = acc[0] + bias, v1 = acc[1] + bias, v2 = acc[2] + bias, v3 = acc[3] + bias;
    float s1 = v0 + v1 + v2 + v3;
    float s2 = v0 * v0 + v1 * v1 + v2 * v2 + v3 * v3;
    s1 += __shfl_xor(s1, 16); s1 += __shfl_xor(s1, 32);
    s2 += __shfl_xor(s2, 16); s2 += __shfl_xor(s2, 32);
    if (lane < 16) {          // lane = n col within tile; [col][64 mt] layout
        sums [(n0 + lane) * 64 + mt] = s1;
        sumsq[(n0 + lane) * 64 + mt] = s2;
    }
    float* Tw = &T[widx][0];  // wave-local transpose slice
    Tw[(kg * 4 + 0) * 20 + row] = v0;
    Tw[(kg * 4 + 1) * 20 + row] = v1;
    Tw[(kg * 4 + 2) * 20 + row] = v2;
    Tw[(kg * 4 + 3) * 20 + row] = v3;
    __syncthreads();
    float4 vv = *(float4*)&Tw[row * 20 + kg * 4];
    *(float4*)(msg2 + (m0 + row) * 256 + n0 + kg * 4) = vv;
}

// ---- K_fin: final BN + residual + unpack to [B,F,N0]|[B,F,N1] --------------
__global__ __launch_bounds__(256) void k_fin(
    const float* __restrict__ x2, const float* __restrict__ msg2,
    const float* __restrict__ sums, const float* __restrict__ sumsq,
    const float* __restrict__ bw, const float* __restrict__ bb,
    float* __restrict__ out) {
    const int blk = blockIdx.x, t = threadIdx.x;
    float s1 = 0.f, s2 = 0.f;
    #pragma unroll
    for (int c = 0; c < 64; c += 4) {
        float4 a4 = *(const float4*)&sums[t * 64 + c];
        float4 b4 = *(const float4*)&sumsq[t * 64 + c];
        s1 += (a4.x + a4.y) + (a4.z + a4.w);
        s2 += (b4.x + b4.y) + (b4.z + b4.w);
    }
    float mu  = s1 * (1.f / 1024.f);
    float var = s2 * (1.f / 1024.f) - mu * mu;
    float scale = bw[t] * rsqrtf(var + 1e-5f);
    float shift = bb[t] - mu * scale;
    #pragma unroll
    for (int j = 0; j < 4; ++j) {
        int node = blk * 4 + j;
        int idx = node * 256 + t;
        float v = x2[idx] + msg2[idx] * scale + shift;
        int b = node >> 8, nl = node & 255, half = nl >> 7, n = nl & 127;
        out[half * 131072 + b * 32768 + t * 128 + n] = v;
    }
}

// ----------------------------------------------------------------------------
extern "C" void kernel_launch(void* const* d_in, const int* in_sizes, int n_in,
                              void* d_out, int out_size, void* d_ws, size_t ws_size,
                              hipStream_t stream) {
    const float* desc0  = (const float*)d_in[0];
    const float* desc1  = (const float*)d_in[1];
    const float* conv_w = (const float*)d_in[2];
    const float* conv_q = (const float*)d_in[3];
    const float* conv_k = (const float*)d_in[4];
    const float* conv_b = (const float*)d_in[5];
    const float* lin_w  = (const float*)d_in[6];
    const float* lin_b  = (const float*)d_in[7];
    const float* bn_w   = (const float*)d_in[8];
    const float* bn_b   = (const float*)d_in[9];
    float* out = (float*)d_out;

    char* p = (char*)d_ws;
    float* x0     = (float*)p; p += 1048576;
    float* x1     = (float*)p; p += 1048576;
    u16*   xb     = (u16*)p;   p += 524288;
    u16*   Wt     = (u16*)p;   p += 786432;    // [3][2][256e][256f]
    u16*   lwb    = (u16*)p;   p += 786432;
    u16*   Ht     = (u16*)p;   p += 1048576;   // [2][256e][1024node]
    float* wqk    = (float*)p; p += 12288;     // [3][4][256]
    float* qkbuf  = (float*)p; p += 16384;     // [4][1024]
    u16*   msg1b  = (u16*)p;   p += 524288;
    float* msg2   = (float*)p; p += 1048576;
    float* sums   = (float*)p; p += 65536;     // [256 col][64 mt]
    float* sumsq  = (float*)p; p += 65536;

    k_prep<<<1024, 256, 0, stream>>>(desc0, desc1, conv_w, lin_w, conv_q, conv_k,
                                     x0, xb, Wt, lwb, wqk);

    // layer i reads xs[i]; writes xs[i+1] only when do_bn (i>0). Layer 0
    // leaves x unchanged, so layer 1 must read x0 again.
    float* xs[4] = {x0, x0, x1, x0};
    for (int i = 0; i < 3; ++i) {
        const u16*   cwt = Wt + i * 131072;
        const u16*   lwp = lwb + i * 131072;
        const float* cb = conv_b + i * 256;
        const float* lb = lin_b + i * 256;
        const float* bwp = bn_w + (i ? (i - 1) * 256 : 0);   // prev-layer BN
        const float* bbp = bn_b + (i ? (i - 1) * 256 : 0);

        k_hqk<<<256, 256, 0, stream>>>(xs[i], msg2, sums, sumsq, bwp, bbp,
                                       cwt, wqk + i * 1024, xs[i + 1], xb, Ht,
                                       qkbuf, i > 0 ? 1 : 0);
        k_attn<<<256, 256, 0, stream>>>(qkbuf, Ht, cb, msg1b);
        k_lin<<<256, 256, 0, stream>>>(xb, msg1b, lwp, lb, msg2, sums, sumsq);
    }

    k_fin<<<256, 256, 0, stream>>>(xs[3], msg2, sums, sumsq,
                                   bn_w + 512, bn_b + 512, out);
}

// Round 10
// 148.604 us; speedup vs baseline: 1.1905x; 1.1905x over previous
//
#include <hip/hip_runtime.h>
#include <math.h>

// B=4 graphs, N=256 nodes (128+128)/graph, F=256, L=3 layers.
// 11 launches: prep + 3x{hqk, attn, lin} + fin — the r5 structure (best
// measured: 157us). Cost model: dur = C(~100us harness fixed) + E(~40us
// kernels) + n*~1.3us. r6-r9 structural variants all regressed; this round is
// r5 byte-identical EXCEPT k_hqk's staging loop is float4-vectorized.
// GEMMs: bf16 MFMA 16x16x32, one wave per 16x16 tile, operands L2-resident.

typedef __attribute__((ext_vector_type(8))) short short8;   // 8 bf16
typedef __attribute__((ext_vector_type(4))) float f32x4;
typedef unsigned short u16;
typedef unsigned int   u32;

__device__ __forceinline__ u16 f2bf(float f) {
    union { float f; u32 u; } v; v.f = f;
    u32 r = v.u + 0x7fffu + ((v.u >> 16) & 1u);     // RNE
    return (u16)(r >> 16);
}
__device__ __forceinline__ short8 ld8(const u16* p) {
    return __builtin_bit_cast(short8, *(const int4*)p);
}

// ---- P0: pack x (fp32+bf16) + transpose conv_w -> Wt + cast lin_w ----------
__global__ __launch_bounds__(256) void k_prep(
    const float* __restrict__ d0, const float* __restrict__ d1,
    const float* __restrict__ conv_w, const float* __restrict__ lin_w,
    float* __restrict__ x, u16* __restrict__ xb,
    u16* __restrict__ Wt, u16* __restrict__ lwb) {
    for (int i = blockIdx.x * 256 + threadIdx.x; i < 1048576; i += 262144) {
        if (i < 262144) {
            int node = i >> 8, f = i & 255, b = node >> 8, nl = node & 255;
            float v = (nl < 128) ? d0[b * 32768 + f * 128 + nl]
                                 : d1[b * 32768 + f * 128 + (nl - 128)];
            x[i] = v; xb[i] = f2bf(v);
        } else if (i < 655360) {
            int o = i - 262144;                     // 6 mats of 256x256
            int mat = o >> 16, rem = o & 65535, e = rem >> 8, f = rem & 255;
            Wt[o] = f2bf(conv_w[mat * 65536 + f * 256 + e]);
        } else {
            int o = i - 655360;
            lwb[o] = f2bf(lin_w[o]);
        }
    }
}

// ---- K1: BN-apply(prev) + H-GEMM -> Ht + qs/ks e-chunk partials ------------
// grid 256 = (64 m-tiles) x (4 e-groups); 256 thr (4 waves). [r5-proven]
// Staging loop float4-vectorized (4 rows/pass, 64 lanes x 16B coalesced);
// BN scale/shift routed through sc/sh LDS (per-col), read as aligned float4.
__global__ __launch_bounds__(256, 1) void k_hqk(
    const float* __restrict__ xprev, const float* __restrict__ msg2,
    const float* __restrict__ sums, const float* __restrict__ sumsq,
    const float* __restrict__ bw, const float* __restrict__ bb,
    const u16* __restrict__ cwt,                 // [2][256 e][256 f]
    const float* __restrict__ cq, const float* __restrict__ ck,
    float* __restrict__ xcur, u16* __restrict__ xb, u16* __restrict__ Ht,
    float* __restrict__ qpart, float* __restrict__ kpart, int do_bn) {
    __shared__ __align__(16) u16 Asub[16 * 264];  // [16 nodes][256 f] bf16
    __shared__ __align__(16) float sc[256];
    __shared__ __align__(16) float sh[256];
    const int tid = threadIdx.x;
    const int mt = blockIdx.x >> 2, eg = blockIdx.x & 3;
    const int m0 = mt * 16;
    const int lane = tid & 63, widx = tid >> 6;
    const int row = lane & 15, kg = lane >> 4;

    if (do_bn) {                                  // col = tid, redundant/block
        float s1 = 0.f, s2 = 0.f;
        #pragma unroll 8
        for (int c = 0; c < 64; ++c) { s1 += sums[c * 256 + tid]; s2 += sumsq[c * 256 + tid]; }
        float mu  = s1 * (1.f / 1024.f);
        float var = s2 * (1.f / 1024.f) - mu * mu;        // biased, as reference
        float scale = bw[tid] * rsqrtf(var + 1e-5f);
        sc[tid] = scale;
        sh[tid] = bb[tid] - mu * scale;
    }
    __syncthreads();
    #pragma unroll
    for (int p = 0; p < 4; ++p) {                 // 4 rows/pass, float4 cols
        const int r = p * 4 + (tid >> 6);
        const int c0 = (tid & 63) * 4;
        const int idx = (m0 + r) * 256 + c0;
        float4 v = *(const float4*)&xprev[idx];
        if (do_bn) {
            float4 m = *(const float4*)&msg2[idx];
            float4 s4 = *(const float4*)&sc[c0];
            float4 h4 = *(const float4*)&sh[c0];
            v.x += m.x * s4.x + h4.x;
            v.y += m.y * s4.y + h4.y;
            v.z += m.z * s4.z + h4.z;
            v.w += m.w * s4.w + h4.w;
        }
        ushort4 hb = {f2bf(v.x), f2bf(v.y), f2bf(v.z), f2bf(v.w)};
        *(ushort4*)&Asub[r * 264 + c0] = hb;      // 528B row stride: 16-aligned
        if (do_bn && eg == 0) {
            *(float4*)&xcur[idx] = v;
            *(ushort4*)&xb[idx] = hb;
        }
    }
    __syncthreads();

    const int et = eg * 4 + widx, e0 = et * 16;   // e-tile 0..15
    const u16* B0 = cwt + (e0 + row) * 256 + kg * 8;
    const u16* B1 = B0 + 65536;
    const u16* Ap = &Asub[row * 264 + kg * 8];
    f32x4 acc0 = {0.f,0.f,0.f,0.f}, acc1 = {0.f,0.f,0.f,0.f};
    #pragma unroll
    for (int k0 = 0; k0 < 256; k0 += 32) {
        short8 a = ld8(Ap + k0);
        acc0 = __builtin_amdgcn_mfma_f32_16x16x32_bf16(a, ld8(B0 + k0), acc0, 0, 0, 0);
        acc1 = __builtin_amdgcn_mfma_f32_16x16x32_bf16(a, ld8(B1 + k0), acc1, 0, 0, 0);
    }
    // D: col(lane&15)=e, row(kg*4+c)=node -> store transposed Ht[r][e][node]
    ushort4 o0, o1;
    o0.x = f2bf(acc0[0]); o0.y = f2bf(acc0[1]); o0.z = f2bf(acc0[2]); o0.w = f2bf(acc0[3]);
    o1.x = f2bf(acc1[0]); o1.y = f2bf(acc1[1]); o1.z = f2bf(acc1[2]); o1.w = f2bf(acc1[3]);
    *(ushort4*)(Ht + (e0 + row) * 1024 + m0 + kg * 4) = o0;
    *(ushort4*)(Ht + 262144 + (e0 + row) * 1024 + m0 + kg * 4) = o1;
    // qs/ks partials over this tile's 16 e's
    float qe = cq[e0 + row], ke = ck[e0 + row];
    float pq0[4], pk0[4], pq1[4], pk1[4];
    #pragma unroll
    for (int c = 0; c < 4; ++c) {
        pq0[c] = acc0[c] * qe; pk0[c] = acc0[c] * ke;
        pq1[c] = acc1[c] * qe; pk1[c] = acc1[c] * ke;
    }
    #pragma unroll
    for (int off = 1; off < 16; off <<= 1) {
        #pragma unroll
        for (int c = 0; c < 4; ++c) {
            pq0[c] += __shfl_xor(pq0[c], off);
            pk0[c] += __shfl_xor(pk0[c], off);
            pq1[c] += __shfl_xor(pq1[c], off);
            pk1[c] += __shfl_xor(pk1[c], off);
        }
    }
    if (row == 0) {
        float4 a4 = {pq0[0], pq0[1], pq0[2], pq0[3]};
        float4 b4 = {pk0[0], pk0[1], pk0[2], pk0[3]};
        float4 c4 = {pq1[0], pq1[1], pq1[2], pq1[3]};
        float4 d4 = {pk1[0], pk1[1], pk1[2], pk1[3]};
        *(float4*)&qpart[et * 1024 + m0 + kg * 4] = a4;
        *(float4*)&kpart[et * 1024 + m0 + kg * 4] = b4;
        *(float4*)&qpart[(16 + et) * 1024 + m0 + kg * 4] = c4;
        *(float4*)&kpart[(16 + et) * 1024 + m0 + kg * 4] = d4;
    }
}

// ---- K2: alpha softmax + attn GEMM + relu/bias -> msg1b [r5-identical] -----
// grid 256 = (64 dst-tiles) x (4 e-groups); 256 thr.
__global__ __launch_bounds__(256, 1) void k_attn(
    const float* __restrict__ qpart, const float* __restrict__ kpart,
    const u16* __restrict__ Ht, const float* __restrict__ cb,
    u16* __restrict__ msg1b) {
    __shared__ __align__(16) u16 Atile[16 * 264]; // alpha bf16 [16 dst][256 src]
    __shared__ float ksl[2][256];
    __shared__ float qsl[2][16];
    __shared__ __align__(16) float T[4][16 * 20];
    const int tid = threadIdx.x;
    const int mt = blockIdx.x >> 2, eg = blockIdx.x & 3;
    const int m0 = mt * 16;
    const int g = mt >> 4, a = (mt >> 3) & 1;
    {   // ks for both relations, this graph's 256 srcs
        float k0s = 0.f, k1s = 0.f;
        #pragma unroll
        for (int c = 0; c < 16; ++c) {
            k0s += kpart[c * 1024 + g * 256 + tid];
            k1s += kpart[(16 + c) * 1024 + g * 256 + tid];
        }
        ksl[0][tid] = k0s; ksl[1][tid] = k1s;
    }
    if (tid < 32) {
        int rel = tid >> 4, r = tid & 15;
        float q = 0.f;
        #pragma unroll
        for (int c = 0; c < 16; ++c) q += qpart[(rel * 16 + c) * 1024 + m0 + r];
        qsl[rel][r] = q;
    }
    __syncthreads();
    {   // softmax: thread = (dst r = tid>>4, src chunk j = tid&15)
        const int r = tid >> 4, j = tid & 15;
        const int dl = (m0 + r) & 255;
        const int s0 = j * 16;
        const int rel = ((s0 >> 7) == a) ? 0 : 1; // chunk never crosses 128
        float qv = qsl[rel][r];
        float l[16], mx = -1e30f;
        #pragma unroll
        for (int i2 = 0; i2 < 16; ++i2) {
            float v = qv + ksl[rel][s0 + i2];
            v = (v >= 0.f) ? v : 0.2f * v;        // leaky_relu 0.2
            if (s0 + i2 == dl) v = -1e30f;        // no self-loop
            l[i2] = v; mx = fmaxf(mx, v);
        }
        #pragma unroll
        for (int off = 1; off < 16; off <<= 1) mx = fmaxf(mx, __shfl_xor(mx, off));
        float s = 0.f;
        #pragma unroll
        for (int i2 = 0; i2 < 16; ++i2) { l[i2] = __expf(l[i2] - mx); s += l[i2]; }
        #pragma unroll
        for (int off = 1; off < 16; off <<= 1) s += __shfl_xor(s, off);
        float inv = 1.f / (s + 1e-16f);
        #pragma unroll
        for (int i2 = 0; i2 < 16; i2 += 2) {
            u32 p = (u32)f2bf(l[i2] * inv) | ((u32)f2bf(l[i2 + 1] * inv) << 16);
            *(u32*)&Atile[r * 264 + s0 + i2] = p;
        }
    }
    __syncthreads();
    const int lane = tid & 63, widx = tid >> 6;
    const int row = lane & 15, kg = lane >> 4;
    const int et = eg * 4 + widx, e0 = et * 16;
    const u16* Ap = &Atile[row * 264 + kg * 8];
    f32x4 acc = {0.f,0.f,0.f,0.f};
    #pragma unroll
    for (int k0 = 0; k0 < 256; k0 += 32) {
        const int rel = (((k0 >> 7) & 1) == a) ? 0 : 1;   // tile-uniform
        const u16* B = Ht + rel * 262144 + (e0 + row) * 1024 + g * 256 + k0 + kg * 8;
        acc = __builtin_amdgcn_mfma_f32_16x16x32_bf16(ld8(Ap + k0), ld8(B), acc, 0, 0, 0);
    }
    float bias = cb[e0 + row];
    float* Tw = &T[widx][0];
    #pragma unroll
    for (int c = 0; c < 4; ++c)
        Tw[(kg * 4 + c) * 20 + row] = fmaxf(acc[c] + bias, 0.f);
    __syncthreads();
    float4 v = *(float4*)&Tw[row * 20 + kg * 4];
    u32 lo = (u32)f2bf(v.x) | ((u32)f2bf(v.y) << 16);
    u32 hi = (u32)f2bf(v.z) | ((u32)f2bf(v.w) << 16);
    uint2 ov = {lo, hi};
    *(uint2*)(msg1b + (m0 + row) * 256 + e0 + kg * 4) = ov;
}

// ---- K3: lin GEMM (K=512) + BN partial stats [r5-identical] ----------------
// grid 256 = (64 m-tiles) x (4 n-groups); 256 thr.
__global__ __launch_bounds__(256, 1) void k_lin(
    const u16* __restrict__ xb, const u16* __restrict__ msg1b,
    const u16* __restrict__ lwp, const float* __restrict__ lb,
    float* __restrict__ msg2, float* __restrict__ sums, float* __restrict__ sumsq) {
    __shared__ __align__(16) float T[4][16 * 20];
    const int tid = threadIdx.x, lane = tid & 63, widx = tid >> 6;
    const int row = lane & 15, kg = lane >> 4;
    const int mt = blockIdx.x >> 2, ng = blockIdx.x & 3;
    const int m0 = mt * 16;
    const int nt = ng * 4 + widx, n0 = nt * 16;
    const u16* A0 = xb    + (m0 + row) * 256 + kg * 8;
    const u16* A1 = msg1b + (m0 + row) * 256 + kg * 8;
    const u16* B  = lwp + (n0 + row) * 512 + kg * 8;
    f32x4 acc = {0.f,0.f,0.f,0.f};
    #pragma unroll
    for (int k0 = 0; k0 < 512; k0 += 32) {
        short8 av = (k0 < 256) ? ld8(A0 + k0) : ld8(A1 + (k0 - 256));
        acc = __builtin_amdgcn_mfma_f32_16x16x32_bf16(av, ld8(B + k0), acc, 0, 0, 0);
    }
    float bias = lb[n0 + row];
    float v0 = acc[0] + bias, v1 = acc[1] + bias, v2 = acc[2] + bias, v3 = acc[3] + bias;
    float s1 = v0 + v1 + v2 + v3;
    float s2 = v0 * v0 + v1 * v1 + v2 * v2 + v3 * v3;
    s1 += __shfl_xor(s1, 16); s1 += __shfl_xor(s1, 32);
    s2 += __shfl_xor(s2, 16); s2 += __shfl_xor(s2, 32);
    if (lane < 16) {          // lane = n col within tile
        sums [mt * 256 + n0 + lane] = s1;
        sumsq[mt * 256 + n0 + lane] = s2;
    }
    float* Tw = &T[widx][0];  // wave-local transpose slice
    Tw[(kg * 4 + 0) * 20 + row] = v0;
    Tw[(kg * 4 + 1) * 20 + row] = v1;
    Tw[(kg * 4 + 2) * 20 + row] = v2;
    Tw[(kg * 4 + 3) * 20 + row] = v3;
    __syncthreads();
    float4 vv = *(float4*)&Tw[row * 20 + kg * 4];
    *(float4*)(msg2 + (m0 + row) * 256 + n0 + kg * 4) = vv;
}

// ---- K_fin: final BN + residual + unpack [r5-identical] --------------------
__global__ __launch_bounds__(256) void k_fin(
    const float* __restrict__ x2, const float* __restrict__ msg2,
    const float* __restrict__ sums, const float* __restrict__ sumsq,
    const float* __restrict__ bw, const float* __restrict__ bb,
    float* __restrict__ out) {
    const int blk = blockIdx.x, t = threadIdx.x;
    float s1 = 0.f, s2 = 0.f;
    #pragma unroll 8
    for (int c = 0; c < 64; ++c) { s1 += sums[c * 256 + t]; s2 += sumsq[c * 256 + t]; }
    float mu  = s1 * (1.f / 1024.f);
    float var = s2 * (1.f / 1024.f) - mu * mu;
    float scale = bw[t] * rsqrtf(var + 1e-5f);
    float shift = bb[t] - mu * scale;
    #pragma unroll
    for (int j = 0; j < 4; ++j) {
        int node = blk * 4 + j;
        int idx = node * 256 + t;
        float v = x2[idx] + msg2[idx] * scale + shift;
        int b = node >> 8, nl = node & 255, half = nl >> 7, n = nl & 127;
        out[half * 131072 + b * 32768 + t * 128 + n] = v;
    }
}

// ----------------------------------------------------------------------------
extern "C" void kernel_launch(void* const* d_in, const int* in_sizes, int n_in,
                              void* d_out, int out_size, void* d_ws, size_t ws_size,
                              hipStream_t stream) {
    const float* desc0  = (const float*)d_in[0];
    const float* desc1  = (const float*)d_in[1];
    const float* conv_w = (const float*)d_in[2];
    const float* conv_q = (const float*)d_in[3];
    const float* conv_k = (const float*)d_in[4];
    const float* conv_b = (const float*)d_in[5];
    const float* lin_w  = (const float*)d_in[6];
    const float* lin_b  = (const float*)d_in[7];
    const float* bn_w   = (const float*)d_in[8];
    const float* bn_b   = (const float*)d_in[9];
    float* out = (float*)d_out;

    char* p = (char*)d_ws;
    float* x0     = (float*)p; p += 1048576;
    float* x1     = (float*)p; p += 1048576;
    u16*   xb     = (u16*)p;   p += 524288;
    u16*   Wt     = (u16*)p;   p += 786432;    // [3][2][256e][256f]
    u16*   lwb    = (u16*)p;   p += 786432;
    u16*   Ht     = (u16*)p;   p += 1048576;   // [2][256e][1024node]
    float* qpart  = (float*)p; p += 131072;    // [32][1024]
    float* kpart  = (float*)p; p += 131072;
    u16*   msg1b  = (u16*)p;   p += 524288;
    float* msg2   = (float*)p; p += 1048576;
    float* sums   = (float*)p; p += 65536;     // [64][256]
    float* sumsq  = (float*)p; p += 65536;

    k_prep<<<1024, 256, 0, stream>>>(desc0, desc1, conv_w, lin_w, x0, xb, Wt, lwb);

    // layer i reads xs[i]; writes xs[i+1] only when do_bn (i>0). Layer 0
    // leaves x unchanged, so layer 1 must read x0 again.
    float* xs[4] = {x0, x0, x1, x0};
    for (int i = 0; i < 3; ++i) {
        const u16*   cwt = Wt + i * 131072;
        const u16*   lwp = lwb + i * 131072;
        const float* cq = conv_q + i * 256;
        const float* ck = conv_k + i * 256;
        const float* cb = conv_b + i * 256;
        const float* lb = lin_b + i * 256;
        const float* bwp = bn_w + (i ? (i - 1) * 256 : 0);   // prev-layer BN
        const float* bbp = bn_b + (i ? (i - 1) * 256 : 0);

        k_hqk<<<256, 256, 0, stream>>>(xs[i], msg2, sums, sumsq, bwp, bbp,
                                       cwt, cq, ck, xs[i + 1], xb, Ht,
                                       qpart, kpart, i > 0 ? 1 : 0);
        k_attn<<<256, 256, 0, stream>>>(qpart, kpart, Ht, cb, msg1b);
        k_lin<<<256, 256, 0, stream>>>(xb, msg1b, lwp, lb, msg2, sums, sumsq);
    }

    k_fin<<<256, 256, 0, stream>>>(xs[3], msg2, sums, sumsq,
                                   bn_w + 512, bn_b + 512, out);
}

// Round 11
// 140.908 us; speedup vs baseline: 1.2555x; 1.0546x over previous
//
#include <hip/hip_runtime.h>
#include <math.h>

// B=4 graphs, N=256 nodes (128+128)/graph, F=256, L=3 layers.
// 11 launches: prep + 3x{hqk, attn, lin} + fin — r10 structure (best: 148.6us).
// This round: k_prep + k_fin rebuilt as 32x32 LDS tile transposes (coalesced
// float4 on both global sides); k_hqk/k_attn/k_lin byte-identical to r10.
// GEMMs: bf16 MFMA 16x16x32, one wave per 16x16 tile, operands L2-resident.

typedef __attribute__((ext_vector_type(8))) short short8;   // 8 bf16
typedef __attribute__((ext_vector_type(4))) float f32x4;
typedef unsigned short u16;
typedef unsigned int   u32;

__device__ __forceinline__ u16 f2bf(float f) {
    union { float f; u32 u; } v; v.f = f;
    u32 r = v.u + 0x7fffu + ((v.u >> 16) & 1u);     // RNE
    return (u16)(r >> 16);
}
__device__ __forceinline__ short8 ld8(const u16* p) {
    return __builtin_bit_cast(short8, *(const int4*)p);
}

// ---- P0: pack x/xb (tile transpose) + Wt transpose + lwb cast --------------
// 1024 blocks x 256 thr. blocks [0,256): pack; [256,640): Wt; [640,1024): lwb.
__global__ __launch_bounds__(256) void k_prep(
    const float* __restrict__ d0, const float* __restrict__ d1,
    const float* __restrict__ conv_w, const float* __restrict__ lin_w,
    float* __restrict__ x, u16* __restrict__ xb,
    u16* __restrict__ Wt, u16* __restrict__ lwb) {
    const int t = threadIdx.x;
    if (blockIdx.x < 256) {
        // pack: d0/d1 [b][f][nl] -> x/xb [b*256+nl][f]; 32f x 32nl tile
        __shared__ float Ts[32 * 33];
        const int tt = blockIdx.x;
        const int b = tt >> 6, rem = tt & 63, ft = rem >> 3, nt = rem & 7;
        const float* src = (nt < 4) ? d0 : d1;
        const int nloc = (nt & 3) * 32;
        {   // read coalesced along nl
            int fr = t >> 3, c4 = t & 7;
            float4 v = *(const float4*)&src[b * 32768 + (ft * 32 + fr) * 128 + nloc + c4 * 4];
            Ts[fr * 33 + c4 * 4 + 0] = v.x;
            Ts[fr * 33 + c4 * 4 + 1] = v.y;
            Ts[fr * 33 + c4 * 4 + 2] = v.z;
            Ts[fr * 33 + c4 * 4 + 3] = v.w;
        }
        __syncthreads();
        {   // write coalesced along f
            int nr = t >> 3, f4 = t & 7;
            float4 v;
            v.x = Ts[(f4 * 4 + 0) * 33 + nr];
            v.y = Ts[(f4 * 4 + 1) * 33 + nr];
            v.z = Ts[(f4 * 4 + 2) * 33 + nr];
            v.w = Ts[(f4 * 4 + 3) * 33 + nr];
            int node = b * 256 + nt * 32 + nr;
            int idx = node * 256 + ft * 32 + f4 * 4;
            *(float4*)&x[idx] = v;
            ushort4 hb = {f2bf(v.x), f2bf(v.y), f2bf(v.z), f2bf(v.w)};
            *(ushort4*)&xb[idx] = hb;
        }
    } else if (blockIdx.x < 640) {
        // Wt: conv_w [mat][f][e] -> Wt [mat][e][f] bf16; 32f x 32e tile
        __shared__ float Ts[32 * 33];
        const int tt = blockIdx.x - 256;
        const int mat = tt >> 6, rem = tt & 63, et = rem >> 3, ft = rem & 7;
        {   // read coalesced along e
            int fr = t >> 3, c4 = t & 7;
            float4 v = *(const float4*)&conv_w[mat * 65536 + (ft * 32 + fr) * 256 + et * 32 + c4 * 4];
            Ts[fr * 33 + c4 * 4 + 0] = v.x;
            Ts[fr * 33 + c4 * 4 + 1] = v.y;
            Ts[fr * 33 + c4 * 4 + 2] = v.z;
            Ts[fr * 33 + c4 * 4 + 3] = v.w;
        }
        __syncthreads();
        {   // write coalesced along f (bf16)
            int er = t >> 3, f4 = t & 7;
            ushort4 hb;
            hb.x = f2bf(Ts[(f4 * 4 + 0) * 33 + er]);
            hb.y = f2bf(Ts[(f4 * 4 + 1) * 33 + er]);
            hb.z = f2bf(Ts[(f4 * 4 + 2) * 33 + er]);
            hb.w = f2bf(Ts[(f4 * 4 + 3) * 33 + er]);
            *(ushort4*)&Wt[mat * 65536 + (et * 32 + er) * 256 + ft * 32 + f4 * 4] = hb;
        }
    } else {
        // lwb: straight bf16 cast, float4 per thread (exactly covers 393216)
        int o4 = (blockIdx.x - 640) * 256 + t;
        float4 v = *(const float4*)&lin_w[o4 * 4];
        ushort4 hb = {f2bf(v.x), f2bf(v.y), f2bf(v.z), f2bf(v.w)};
        *(ushort4*)&lwb[o4 * 4] = hb;
    }
}

// ---- K1: BN-apply(prev) + H-GEMM -> Ht + qs/ks e-chunk partials ------------
// grid 256 = (64 m-tiles) x (4 e-groups); 256 thr (4 waves). [r10-identical]
__global__ __launch_bounds__(256, 1) void k_hqk(
    const float* __restrict__ xprev, const float* __restrict__ msg2,
    const float* __restrict__ sums, const float* __restrict__ sumsq,
    const float* __restrict__ bw, const float* __restrict__ bb,
    const u16* __restrict__ cwt,                 // [2][256 e][256 f]
    const float* __restrict__ cq, const float* __restrict__ ck,
    float* __restrict__ xcur, u16* __restrict__ xb, u16* __restrict__ Ht,
    float* __restrict__ qpart, float* __restrict__ kpart, int do_bn) {
    __shared__ __align__(16) u16 Asub[16 * 264];  // [16 nodes][256 f] bf16
    __shared__ __align__(16) float sc[256];
    __shared__ __align__(16) float sh[256];
    const int tid = threadIdx.x;
    const int mt = blockIdx.x >> 2, eg = blockIdx.x & 3;
    const int m0 = mt * 16;
    const int lane = tid & 63, widx = tid >> 6;
    const int row = lane & 15, kg = lane >> 4;

    if (do_bn) {                                  // col = tid, redundant/block
        float s1 = 0.f, s2 = 0.f;
        #pragma unroll 8
        for (int c = 0; c < 64; ++c) { s1 += sums[c * 256 + tid]; s2 += sumsq[c * 256 + tid]; }
        float mu  = s1 * (1.f / 1024.f);
        float var = s2 * (1.f / 1024.f) - mu * mu;        // biased, as reference
        float scale = bw[tid] * rsqrtf(var + 1e-5f);
        sc[tid] = scale;
        sh[tid] = bb[tid] - mu * scale;
    }
    __syncthreads();
    #pragma unroll
    for (int p = 0; p < 4; ++p) {                 // 4 rows/pass, float4 cols
        const int r = p * 4 + (tid >> 6);
        const int c0 = (tid & 63) * 4;
        const int idx = (m0 + r) * 256 + c0;
        float4 v = *(const float4*)&xprev[idx];
        if (do_bn) {
            float4 m = *(const float4*)&msg2[idx];
            float4 s4 = *(const float4*)&sc[c0];
            float4 h4 = *(const float4*)&sh[c0];
            v.x += m.x * s4.x + h4.x;
            v.y += m.y * s4.y + h4.y;
            v.z += m.z * s4.z + h4.z;
            v.w += m.w * s4.w + h4.w;
        }
        ushort4 hb = {f2bf(v.x), f2bf(v.y), f2bf(v.z), f2bf(v.w)};
        *(ushort4*)&Asub[r * 264 + c0] = hb;      // 528B row stride: 16-aligned
        if (do_bn && eg == 0) {
            *(float4*)&xcur[idx] = v;
            *(ushort4*)&xb[idx] = hb;
        }
    }
    __syncthreads();

    const int et = eg * 4 + widx, e0 = et * 16;   // e-tile 0..15
    const u16* B0 = cwt + (e0 + row) * 256 + kg * 8;
    const u16* B1 = B0 + 65536;
    const u16* Ap = &Asub[row * 264 + kg * 8];
    f32x4 acc0 = {0.f,0.f,0.f,0.f}, acc1 = {0.f,0.f,0.f,0.f};
    #pragma unroll
    for (int k0 = 0; k0 < 256; k0 += 32) {
        short8 a = ld8(Ap + k0);
        acc0 = __builtin_amdgcn_mfma_f32_16x16x32_bf16(a, ld8(B0 + k0), acc0, 0, 0, 0);
        acc1 = __builtin_amdgcn_mfma_f32_16x16x32_bf16(a, ld8(B1 + k0), acc1, 0, 0, 0);
    }
    // D: col(lane&15)=e, row(kg*4+c)=node -> store transposed Ht[r][e][node]
    ushort4 o0, o1;
    o0.x = f2bf(acc0[0]); o0.y = f2bf(acc0[1]); o0.z = f2bf(acc0[2]); o0.w = f2bf(acc0[3]);
    o1.x = f2bf(acc1[0]); o1.y = f2bf(acc1[1]); o1.z = f2bf(acc1[2]); o1.w = f2bf(acc1[3]);
    *(ushort4*)(Ht + (e0 + row) * 1024 + m0 + kg * 4) = o0;
    *(ushort4*)(Ht + 262144 + (e0 + row) * 1024 + m0 + kg * 4) = o1;
    // qs/ks partials over this tile's 16 e's
    float qe = cq[e0 + row], ke = ck[e0 + row];
    float pq0[4], pk0[4], pq1[4], pk1[4];
    #pragma unroll
    for (int c = 0; c < 4; ++c) {
        pq0[c] = acc0[c] * qe; pk0[c] = acc0[c] * ke;
        pq1[c] = acc1[c] * qe; pk1[c] = acc1[c] * ke;
    }
    #pragma unroll
    for (int off = 1; off < 16; off <<= 1) {
        #pragma unroll
        for (int c = 0; c < 4; ++c) {
            pq0[c] += __shfl_xor(pq0[c], off);
            pk0[c] += __shfl_xor(pk0[c], off);
            pq1[c] += __shfl_xor(pq1[c], off);
            pk1[c] += __shfl_xor(pk1[c], off);
        }
    }
    if (row == 0) {
        float4 a4 = {pq0[0], pq0[1], pq0[2], pq0[3]};
        float4 b4 = {pk0[0], pk0[1], pk0[2], pk0[3]};
        float4 c4 = {pq1[0], pq1[1], pq1[2], pq1[3]};
        float4 d4 = {pk1[0], pk1[1], pk1[2], pk1[3]};
        *(float4*)&qpart[et * 1024 + m0 + kg * 4] = a4;
        *(float4*)&kpart[et * 1024 + m0 + kg * 4] = b4;
        *(float4*)&qpart[(16 + et) * 1024 + m0 + kg * 4] = c4;
        *(float4*)&kpart[(16 + et) * 1024 + m0 + kg * 4] = d4;
    }
}

// ---- K2: alpha softmax + attn GEMM + relu/bias -> msg1b [r10-identical] ----
// grid 256 = (64 dst-tiles) x (4 e-groups); 256 thr.
__global__ __launch_bounds__(256, 1) void k_attn(
    const float* __restrict__ qpart, const float* __restrict__ kpart,
    const u16* __restrict__ Ht, const float* __restrict__ cb,
    u16* __restrict__ msg1b) {
    __shared__ __align__(16) u16 Atile[16 * 264]; // alpha bf16 [16 dst][256 src]
    __shared__ float ksl[2][256];
    __shared__ float qsl[2][16];
    __shared__ __align__(16) float T[4][16 * 20];
    const int tid = threadIdx.x;
    const int mt = blockIdx.x >> 2, eg = blockIdx.x & 3;
    const int m0 = mt * 16;
    const int g = mt >> 4, a = (mt >> 3) & 1;
    {   // ks for both relations, this graph's 256 srcs
        float k0s = 0.f, k1s = 0.f;
        #pragma unroll
        for (int c = 0; c < 16; ++c) {
            k0s += kpart[c * 1024 + g * 256 + tid];
            k1s += kpart[(16 + c) * 1024 + g * 256 + tid];
        }
        ksl[0][tid] = k0s; ksl[1][tid] = k1s;
    }
    if (tid < 32) {
        int rel = tid >> 4, r = tid & 15;
        float q = 0.f;
        #pragma unroll
        for (int c = 0; c < 16; ++c) q += qpart[(rel * 16 + c) * 1024 + m0 + r];
        qsl[rel][r] = q;
    }
    __syncthreads();
    {   // softmax: thread = (dst r = tid>>4, src chunk j = tid&15)
        const int r = tid >> 4, j = tid & 15;
        const int dl = (m0 + r) & 255;
        const int s0 = j * 16;
        const int rel = ((s0 >> 7) == a) ? 0 : 1; // chunk never crosses 128
        float qv = qsl[rel][r];
        float l[16], mx = -1e30f;
        #pragma unroll
        for (int i2 = 0; i2 < 16; ++i2) {
            float v = qv + ksl[rel][s0 + i2];
            v = (v >= 0.f) ? v : 0.2f * v;        // leaky_relu 0.2
            if (s0 + i2 == dl) v = -1e30f;        // no self-loop
            l[i2] = v; mx = fmaxf(mx, v);
        }
        #pragma unroll
        for (int off = 1; off < 16; off <<= 1) mx = fmaxf(mx, __shfl_xor(mx, off));
        float s = 0.f;
        #pragma unroll
        for (int i2 = 0; i2 < 16; ++i2) { l[i2] = __expf(l[i2] - mx); s += l[i2]; }
        #pragma unroll
        for (int off = 1; off < 16; off <<= 1) s += __shfl_xor(s, off);
        float inv = 1.f / (s + 1e-16f);
        #pragma unroll
        for (int i2 = 0; i2 < 16; i2 += 2) {
            u32 p = (u32)f2bf(l[i2] * inv) | ((u32)f2bf(l[i2 + 1] * inv) << 16);
            *(u32*)&Atile[r * 264 + s0 + i2] = p;
        }
    }
    __syncthreads();
    const int lane = tid & 63, widx = tid >> 6;
    const int row = lane & 15, kg = lane >> 4;
    const int et = eg * 4 + widx, e0 = et * 16;
    const u16* Ap = &Atile[row * 264 + kg * 8];
    f32x4 acc = {0.f,0.f,0.f,0.f};
    #pragma unroll
    for (int k0 = 0; k0 < 256; k0 += 32) {
        const int rel = (((k0 >> 7) & 1) == a) ? 0 : 1;   // tile-uniform
        const u16* B = Ht + rel * 262144 + (e0 + row) * 1024 + g * 256 + k0 + kg * 8;
        acc = __builtin_amdgcn_mfma_f32_16x16x32_bf16(ld8(Ap + k0), ld8(B), acc, 0, 0, 0);
    }
    float bias = cb[e0 + row];
    float* Tw = &T[widx][0];
    #pragma unroll
    for (int c = 0; c < 4; ++c)
        Tw[(kg * 4 + c) * 20 + row] = fmaxf(acc[c] + bias, 0.f);
    __syncthreads();
    float4 v = *(float4*)&Tw[row * 20 + kg * 4];
    u32 lo = (u32)f2bf(v.x) | ((u32)f2bf(v.y) << 16);
    u32 hi = (u32)f2bf(v.z) | ((u32)f2bf(v.w) << 16);
    uint2 ov = {lo, hi};
    *(uint2*)(msg1b + (m0 + row) * 256 + e0 + kg * 4) = ov;
}

// ---- K3: lin GEMM (K=512) + BN partial stats [r10-identical] ---------------
// grid 256 = (64 m-tiles) x (4 n-groups); 256 thr.
__global__ __launch_bounds__(256, 1) void k_lin(
    const u16* __restrict__ xb, const u16* __restrict__ msg1b,
    const u16* __restrict__ lwp, const float* __restrict__ lb,
    float* __restrict__ msg2, float* __restrict__ sums, float* __restrict__ sumsq) {
    __shared__ __align__(16) float T[4][16 * 20];
    const int tid = threadIdx.x, lane = tid & 63, widx = tid >> 6;
    const int row = lane & 15, kg = lane >> 4;
    const int mt = blockIdx.x >> 2, ng = blockIdx.x & 3;
    const int m0 = mt * 16;
    const int nt = ng * 4 + widx, n0 = nt * 16;
    const u16* A0 = xb    + (m0 + row) * 256 + kg * 8;
    const u16* A1 = msg1b + (m0 + row) * 256 + kg * 8;
    const u16* B  = lwp + (n0 + row) * 512 + kg * 8;
    f32x4 acc = {0.f,0.f,0.f,0.f};
    #pragma unroll
    for (int k0 = 0; k0 < 512; k0 += 32) {
        short8 av = (k0 < 256) ? ld8(A0 + k0) : ld8(A1 + (k0 - 256));
        acc = __builtin_amdgcn_mfma_f32_16x16x32_bf16(av, ld8(B + k0), acc, 0, 0, 0);
    }
    float bias = lb[n0 + row];
    float v0 = acc[0] + bias, v1 = acc[1] + bias, v2 = acc[2] + bias, v3 = acc[3] + bias;
    float s1 = v0 + v1 + v2 + v3;
    float s2 = v0 * v0 + v1 * v1 + v2 * v2 + v3 * v3;
    s1 += __shfl_xor(s1, 16); s1 += __shfl_xor(s1, 32);
    s2 += __shfl_xor(s2, 16); s2 += __shfl_xor(s2, 32);
    if (lane < 16) {          // lane = n col within tile
        sums [mt * 256 + n0 + lane] = s1;
        sumsq[mt * 256 + n0 + lane] = s2;
    }
    float* Tw = &T[widx][0];  // wave-local transpose slice
    Tw[(kg * 4 + 0) * 20 + row] = v0;
    Tw[(kg * 4 + 1) * 20 + row] = v1;
    Tw[(kg * 4 + 2) * 20 + row] = v2;
    Tw[(kg * 4 + 3) * 20 + row] = v3;
    __syncthreads();
    float4 vv = *(float4*)&Tw[row * 20 + kg * 4];
    *(float4*)&msg2[(m0 + row) * 256 + n0 + kg * 4] = vv;
}

// ---- K_fin: final BN + residual + unpack via 32x32 tile transpose ----------
// grid 256 = (32 node-tiles) x (8 f-tiles); 256 thr. Coalesced both sides.
__global__ __launch_bounds__(256) void k_fin(
    const float* __restrict__ x2, const float* __restrict__ msg2,
    const float* __restrict__ sums, const float* __restrict__ sumsq,
    const float* __restrict__ bw, const float* __restrict__ bb,
    float* __restrict__ out) {
    __shared__ float Tt[32 * 33];
    __shared__ float ps1[32 * 9];
    __shared__ float ps2[32 * 9];
    __shared__ float scf[32];
    __shared__ float shf[32];
    const int t = threadIdx.x;
    const int nt2 = blockIdx.x >> 3, ft = blockIdx.x & 7;
    const int n0 = nt2 * 32, f0 = ft * 32;
    {   // BN stats for this tile's 32 f: partial over 8 c's, then reduce
        const int fl = t & 31, chunk = t >> 5;
        float s1 = 0.f, s2 = 0.f;
        #pragma unroll
        for (int j = 0; j < 8; ++j) {
            s1 += sums [(chunk * 8 + j) * 256 + f0 + fl];
            s2 += sumsq[(chunk * 8 + j) * 256 + f0 + fl];
        }
        ps1[fl * 9 + chunk] = s1;
        ps2[fl * 9 + chunk] = s2;
    }
    __syncthreads();
    if (t < 32) {
        float s1 = 0.f, s2 = 0.f;
        #pragma unroll
        for (int c = 0; c < 8; ++c) { s1 += ps1[t * 9 + c]; s2 += ps2[t * 9 + c]; }
        float mu  = s1 * (1.f / 1024.f);
        float var = s2 * (1.f / 1024.f) - mu * mu;    // biased, as reference
        float scale = bw[f0 + t] * rsqrtf(var + 1e-5f);
        scf[t] = scale;
        shf[t] = bb[f0 + t] - mu * scale;
    }
    __syncthreads();
    {   // stage BN(x2+msg2) into LDS transposed: Tt[f][node]
        const int nr = t >> 3, f4 = t & 7;
        const int idx = (n0 + nr) * 256 + f0 + f4 * 4;
        float4 v = *(const float4*)&x2[idx];
        float4 m = *(const float4*)&msg2[idx];
        v.x += m.x * scf[f4 * 4 + 0] + shf[f4 * 4 + 0];
        v.y += m.y * scf[f4 * 4 + 1] + shf[f4 * 4 + 1];
        v.z += m.z * scf[f4 * 4 + 2] + shf[f4 * 4 + 2];
        v.w += m.w * scf[f4 * 4 + 3] + shf[f4 * 4 + 3];
        Tt[(f4 * 4 + 0) * 33 + nr] = v.x;
        Tt[(f4 * 4 + 1) * 33 + nr] = v.y;
        Tt[(f4 * 4 + 2) * 33 + nr] = v.z;
        Tt[(f4 * 4 + 3) * 33 + nr] = v.w;
    }
    __syncthreads();
    {   // write out[half][b][f][n] coalesced along n
        const int fr = t >> 3, n4 = t & 7;
        const int b = n0 >> 8, half = (n0 >> 7) & 1, nloc = n0 & 127;
        float4 v;
        v.x = Tt[fr * 33 + n4 * 4 + 0];
        v.y = Tt[fr * 33 + n4 * 4 + 1];
        v.z = Tt[fr * 33 + n4 * 4 + 2];
        v.w = Tt[fr * 33 + n4 * 4 + 3];
        *(float4*)&out[half * 131072 + b * 32768 + (f0 + fr) * 128 + nloc + n4 * 4] = v;
    }
}

// ----------------------------------------------------------------------------
extern "C" void kernel_launch(void* const* d_in, const int* in_sizes, int n_in,
                              void* d_out, int out_size, void* d_ws, size_t ws_size,
                              hipStream_t stream) {
    const float* desc0  = (const float*)d_in[0];
    const float* desc1  = (const float*)d_in[1];
    const float* conv_w = (const float*)d_in[2];
    const float* conv_q = (const float*)d_in[3];
    const float* conv_k = (const float*)d_in[4];
    const float* conv_b = (const float*)d_in[5];
    const float* lin_w  = (const float*)d_in[6];
    const float* lin_b  = (const float*)d_in[7];
    const float* bn_w   = (const float*)d_in[8];
    const float* bn_b   = (const float*)d_in[9];
    float* out = (float*)d_out;

    char* p = (char*)d_ws;
    float* x0     = (float*)p; p += 1048576;
    float* x1     = (float*)p; p += 1048576;
    u16*   xb     = (u16*)p;   p += 524288;
    u16*   Wt     = (u16*)p;   p += 786432;    // [3][2][256e][256f]
    u16*   lwb    = (u16*)p;   p += 786432;
    u16*   Ht     = (u16*)p;   p += 1048576;   // [2][256e][1024node]
    float* qpart  = (float*)p; p += 131072;    // [32][1024]
    float* kpart  = (float*)p; p += 131072;
    u16*   msg1b  = (u16*)p;   p += 524288;
    float* msg2   = (float*)p; p += 1048576;
    float* sums   = (float*)p; p += 65536;     // [64][256]
    float* sumsq  = (float*)p; p += 65536;

    k_prep<<<1024, 256, 0, stream>>>(desc0, desc1, conv_w, lin_w, x0, xb, Wt, lwb);

    // layer i reads xs[i]; writes xs[i+1] only when do_bn (i>0). Layer 0
    // leaves x unchanged, so layer 1 must read x0 again.
    float* xs[4] = {x0, x0, x1, x0};
    for (int i = 0; i < 3; ++i) {
        const u16*   cwt = Wt + i * 131072;
        const u16*   lwp = lwb + i * 131072;
        const float* cq = conv_q + i * 256;
        const float* ck = conv_k + i * 256;
        const float* cb = conv_b + i * 256;
        const float* lb = lin_b + i * 256;
        const float* bwp = bn_w + (i ? (i - 1) * 256 : 0);   // prev-layer BN
        const float* bbp = bn_b + (i ? (i - 1) * 256 : 0);

        k_hqk<<<256, 256, 0, stream>>>(xs[i], msg2, sums, sumsq, bwp, bbp,
                                       cwt, cq, ck, xs[i + 1], xb, Ht,
                                       qpart, kpart, i > 0 ? 1 : 0);
        k_attn<<<256, 256, 0, stream>>>(qpart, kpart, Ht, cb, msg1b);
        k_lin<<<256, 256, 0, stream>>>(xb, msg1b, lwp, lb, msg2, sums, sumsq);
    }

    k_fin<<<256, 256, 0, stream>>>(xs[3], msg2, sums, sumsq,
                                   bn_w + 512, bn_b + 512, out);
}

// Round 12
// 139.518 us; speedup vs baseline: 1.2680x; 1.0100x over previous
//
#include <hip/hip_runtime.h>
#include <math.h>

// B=4 graphs, N=256 nodes (128+128)/graph, F=256, L=3 layers.
// 11 launches: prep + 3x{hqk, attn, lin} + fin (r11 base: 140.9us).
// This round: (1) BN stats via atomicAdd into gsum/gsumsq[256] (k_attn blk0
// zeroes; launch boundaries order zero->accum->consume), killing the
// O(blocks^2) partial re-read; (2) k_hqk 512 blocks (rel-split waves) and
// k_lin 512x128 (wave-local, barrier-free) for 2 blocks/CU latency overlap.
// GEMMs: bf16 MFMA 16x16x32, one wave per 16x16 tile, operands L2-resident.

typedef __attribute__((ext_vector_type(8))) short short8;   // 8 bf16
typedef __attribute__((ext_vector_type(4))) float f32x4;
typedef unsigned short u16;
typedef unsigned int   u32;

__device__ __forceinline__ u16 f2bf(float f) {
    union { float f; u32 u; } v; v.f = f;
    u32 r = v.u + 0x7fffu + ((v.u >> 16) & 1u);     // RNE
    return (u16)(r >> 16);
}
__device__ __forceinline__ short8 ld8(const u16* p) {
    return __builtin_bit_cast(short8, *(const int4*)p);
}

// ---- P0: pack x/xb (tile transpose) + Wt transpose + lwb cast [r11] --------
__global__ __launch_bounds__(256) void k_prep(
    const float* __restrict__ d0, const float* __restrict__ d1,
    const float* __restrict__ conv_w, const float* __restrict__ lin_w,
    float* __restrict__ x, u16* __restrict__ xb,
    u16* __restrict__ Wt, u16* __restrict__ lwb) {
    const int t = threadIdx.x;
    if (blockIdx.x < 256) {
        __shared__ float Ts[32 * 33];
        const int tt = blockIdx.x;
        const int b = tt >> 6, rem = tt & 63, ft = rem >> 3, nt = rem & 7;
        const float* src = (nt < 4) ? d0 : d1;
        const int nloc = (nt & 3) * 32;
        {   // read coalesced along nl
            int fr = t >> 3, c4 = t & 7;
            float4 v = *(const float4*)&src[b * 32768 + (ft * 32 + fr) * 128 + nloc + c4 * 4];
            Ts[fr * 33 + c4 * 4 + 0] = v.x;
            Ts[fr * 33 + c4 * 4 + 1] = v.y;
            Ts[fr * 33 + c4 * 4 + 2] = v.z;
            Ts[fr * 33 + c4 * 4 + 3] = v.w;
        }
        __syncthreads();
        {   // write coalesced along f
            int nr = t >> 3, f4 = t & 7;
            float4 v;
            v.x = Ts[(f4 * 4 + 0) * 33 + nr];
            v.y = Ts[(f4 * 4 + 1) * 33 + nr];
            v.z = Ts[(f4 * 4 + 2) * 33 + nr];
            v.w = Ts[(f4 * 4 + 3) * 33 + nr];
            int node = b * 256 + nt * 32 + nr;
            int idx = node * 256 + ft * 32 + f4 * 4;
            *(float4*)&x[idx] = v;
            ushort4 hb = {f2bf(v.x), f2bf(v.y), f2bf(v.z), f2bf(v.w)};
            *(ushort4*)&xb[idx] = hb;
        }
    } else if (blockIdx.x < 640) {
        __shared__ float Ts[32 * 33];
        const int tt = blockIdx.x - 256;
        const int mat = tt >> 6, rem = tt & 63, et = rem >> 3, ft = rem & 7;
        {   // read coalesced along e
            int fr = t >> 3, c4 = t & 7;
            float4 v = *(const float4*)&conv_w[mat * 65536 + (ft * 32 + fr) * 256 + et * 32 + c4 * 4];
            Ts[fr * 33 + c4 * 4 + 0] = v.x;
            Ts[fr * 33 + c4 * 4 + 1] = v.y;
            Ts[fr * 33 + c4 * 4 + 2] = v.z;
            Ts[fr * 33 + c4 * 4 + 3] = v.w;
        }
        __syncthreads();
        {   // write coalesced along f (bf16)
            int er = t >> 3, f4 = t & 7;
            ushort4 hb;
            hb.x = f2bf(Ts[(f4 * 4 + 0) * 33 + er]);
            hb.y = f2bf(Ts[(f4 * 4 + 1) * 33 + er]);
            hb.z = f2bf(Ts[(f4 * 4 + 2) * 33 + er]);
            hb.w = f2bf(Ts[(f4 * 4 + 3) * 33 + er]);
            *(ushort4*)&Wt[mat * 65536 + (et * 32 + er) * 256 + ft * 32 + f4 * 4] = hb;
        }
    } else {
        int o4 = (blockIdx.x - 640) * 256 + t;
        float4 v = *(const float4*)&lin_w[o4 * 4];
        ushort4 hb = {f2bf(v.x), f2bf(v.y), f2bf(v.z), f2bf(v.w)};
        *(ushort4*)&lwb[o4 * 4] = hb;
    }
}

// ---- K1: BN-apply(prev) + H-GEMM -> Ht + qs/ks partials --------------------
// grid 512 = (64 m-tiles) x (8: rel*4+eg); 256 thr. One relation per block.
__global__ __launch_bounds__(256, 1) void k_hqk(
    const float* __restrict__ xprev, const float* __restrict__ msg2,
    const float* __restrict__ gsum, const float* __restrict__ gsumsq, // [256]
    const float* __restrict__ bw, const float* __restrict__ bb,
    const u16* __restrict__ cwt,                 // [2][256 e][256 f]
    const float* __restrict__ cq, const float* __restrict__ ck,
    float* __restrict__ xcur, u16* __restrict__ xb, u16* __restrict__ Ht,
    float* __restrict__ qpart, float* __restrict__ kpart, int do_bn) {
    __shared__ __align__(16) u16 Asub[16 * 264];  // [16 nodes][256 f] bf16
    __shared__ __align__(16) float sc[256];
    __shared__ __align__(16) float sh[256];
    const int tid = threadIdx.x;
    const int mt = blockIdx.x >> 3, sg = blockIdx.x & 7;
    const int rel = sg >> 2, eg = sg & 3;
    const int m0 = mt * 16;
    const int lane = tid & 63, widx = tid >> 6;
    const int row = lane & 15, kg = lane >> 4;

    if (do_bn) {                                  // 2-load BN (atomic gsum)
        float s1 = gsum[tid], s2 = gsumsq[tid];
        float mu  = s1 * (1.f / 1024.f);
        float var = s2 * (1.f / 1024.f) - mu * mu;        // biased, as reference
        float scale = bw[tid] * rsqrtf(var + 1e-5f);
        sc[tid] = scale;
        sh[tid] = bb[tid] - mu * scale;
    }
    __syncthreads();
    #pragma unroll
    for (int p = 0; p < 4; ++p) {                 // 4 rows/pass, float4 cols
        const int r = p * 4 + (tid >> 6);
        const int c0 = (tid & 63) * 4;
        const int idx = (m0 + r) * 256 + c0;
        float4 v = *(const float4*)&xprev[idx];
        if (do_bn) {
            float4 m = *(const float4*)&msg2[idx];
            float4 s4 = *(const float4*)&sc[c0];
            float4 h4 = *(const float4*)&sh[c0];
            v.x += m.x * s4.x + h4.x;
            v.y += m.y * s4.y + h4.y;
            v.z += m.z * s4.z + h4.z;
            v.w += m.w * s4.w + h4.w;
        }
        ushort4 hb = {f2bf(v.x), f2bf(v.y), f2bf(v.z), f2bf(v.w)};
        *(ushort4*)&Asub[r * 264 + c0] = hb;
        if (do_bn && sg == 0) {
            *(float4*)&xcur[idx] = v;
            *(ushort4*)&xb[idx] = hb;
        }
    }
    __syncthreads();

    const int et = eg * 4 + widx, e0 = et * 16;   // e-tile 0..15 (this rel)
    const u16* B = cwt + rel * 65536 + (e0 + row) * 256 + kg * 8;
    const u16* Ap = &Asub[row * 264 + kg * 8];
    f32x4 acc = {0.f,0.f,0.f,0.f};
    #pragma unroll
    for (int k0 = 0; k0 < 256; k0 += 32)
        acc = __builtin_amdgcn_mfma_f32_16x16x32_bf16(ld8(Ap + k0), ld8(B + k0), acc, 0, 0, 0);
    // D: col(lane&15)=e, row(kg*4+c)=node -> store transposed Ht[rel][e][node]
    ushort4 o0;
    o0.x = f2bf(acc[0]); o0.y = f2bf(acc[1]); o0.z = f2bf(acc[2]); o0.w = f2bf(acc[3]);
    *(ushort4*)(Ht + rel * 262144 + (e0 + row) * 1024 + m0 + kg * 4) = o0;
    // qs/ks partials over this tile's 16 e's
    float qe = cq[e0 + row], ke = ck[e0 + row];
    float pq[4], pk[4];
    #pragma unroll
    for (int c = 0; c < 4; ++c) { pq[c] = acc[c] * qe; pk[c] = acc[c] * ke; }
    #pragma unroll
    for (int off = 1; off < 16; off <<= 1) {
        #pragma unroll
        for (int c = 0; c < 4; ++c) {
            pq[c] += __shfl_xor(pq[c], off);
            pk[c] += __shfl_xor(pk[c], off);
        }
    }
    if (row == 0) {
        float4 a4 = {pq[0], pq[1], pq[2], pq[3]};
        float4 b4 = {pk[0], pk[1], pk[2], pk[3]};
        *(float4*)&qpart[(rel * 16 + et) * 1024 + m0 + kg * 4] = a4;
        *(float4*)&kpart[(rel * 16 + et) * 1024 + m0 + kg * 4] = b4;
    }
}

// ---- K2: alpha softmax + attn GEMM + relu/bias -> msg1b --------------------
// grid 256 = (64 dst-tiles) x (4 e-groups); 256 thr. Block 0 zeroes gsum.
__global__ __launch_bounds__(256, 1) void k_attn(
    const float* __restrict__ qpart, const float* __restrict__ kpart,
    const u16* __restrict__ Ht, const float* __restrict__ cb,
    u16* __restrict__ msg1b, float* __restrict__ gsum, float* __restrict__ gsumsq) {
    __shared__ __align__(16) u16 Atile[16 * 264]; // alpha bf16 [16 dst][256 src]
    __shared__ float ksl[2][256];
    __shared__ float qsl[2][16];
    __shared__ __align__(16) float T[4][16 * 20];
    const int tid = threadIdx.x;
    const int mt = blockIdx.x >> 2, eg = blockIdx.x & 3;
    const int m0 = mt * 16;
    const int g = mt >> 4, a = (mt >> 3) & 1;
    if (blockIdx.x == 0) { gsum[tid] = 0.f; gsumsq[tid] = 0.f; }  // for k_lin
    {   // ks for both relations, this graph's 256 srcs
        float k0s = 0.f, k1s = 0.f;
        #pragma unroll
        for (int c = 0; c < 16; ++c) {
            k0s += kpart[c * 1024 + g * 256 + tid];
            k1s += kpart[(16 + c) * 1024 + g * 256 + tid];
        }
        ksl[0][tid] = k0s; ksl[1][tid] = k1s;
    }
    if (tid < 32) {
        int rel = tid >> 4, r = tid & 15;
        float q = 0.f;
        #pragma unroll
        for (int c = 0; c < 16; ++c) q += qpart[(rel * 16 + c) * 1024 + m0 + r];
        qsl[rel][r] = q;
    }
    __syncthreads();
    {   // softmax: thread = (dst r = tid>>4, src chunk j = tid&15)
        const int r = tid >> 4, j = tid & 15;
        const int dl = (m0 + r) & 255;
        const int s0 = j * 16;
        const int rel = ((s0 >> 7) == a) ? 0 : 1; // chunk never crosses 128
        float qv = qsl[rel][r];
        float l[16], mx = -1e30f;
        #pragma unroll
        for (int i2 = 0; i2 < 16; ++i2) {
            float v = qv + ksl[rel][s0 + i2];
            v = (v >= 0.f) ? v : 0.2f * v;        // leaky_relu 0.2
            if (s0 + i2 == dl) v = -1e30f;        // no self-loop
            l[i2] = v; mx = fmaxf(mx, v);
        }
        #pragma unroll
        for (int off = 1; off < 16; off <<= 1) mx = fmaxf(mx, __shfl_xor(mx, off));
        float s = 0.f;
        #pragma unroll
        for (int i2 = 0; i2 < 16; ++i2) { l[i2] = __expf(l[i2] - mx); s += l[i2]; }
        #pragma unroll
        for (int off = 1; off < 16; off <<= 1) s += __shfl_xor(s, off);
        float inv = 1.f / (s + 1e-16f);
        #pragma unroll
        for (int i2 = 0; i2 < 16; i2 += 2) {
            u32 p = (u32)f2bf(l[i2] * inv) | ((u32)f2bf(l[i2 + 1] * inv) << 16);
            *(u32*)&Atile[r * 264 + s0 + i2] = p;
        }
    }
    __syncthreads();
    const int lane = tid & 63, widx = tid >> 6;
    const int row = lane & 15, kg = lane >> 4;
    const int et = eg * 4 + widx, e0 = et * 16;
    const u16* Ap = &Atile[row * 264 + kg * 8];
    f32x4 acc = {0.f,0.f,0.f,0.f};
    #pragma unroll
    for (int k0 = 0; k0 < 256; k0 += 32) {
        const int rel = (((k0 >> 7) & 1) == a) ? 0 : 1;   // tile-uniform
        const u16* B = Ht + rel * 262144 + (e0 + row) * 1024 + g * 256 + k0 + kg * 8;
        acc = __builtin_amdgcn_mfma_f32_16x16x32_bf16(ld8(Ap + k0), ld8(B), acc, 0, 0, 0);
    }
    float bias = cb[e0 + row];
    float* Tw = &T[widx][0];
    #pragma unroll
    for (int c = 0; c < 4; ++c)
        Tw[(kg * 4 + c) * 20 + row] = fmaxf(acc[c] + bias, 0.f);
    __syncthreads();
    float4 v = *(float4*)&Tw[row * 20 + kg * 4];
    u32 lo = (u32)f2bf(v.x) | ((u32)f2bf(v.y) << 16);
    u32 hi = (u32)f2bf(v.z) | ((u32)f2bf(v.w) << 16);
    uint2 ov = {lo, hi};
    *(uint2*)(msg1b + (m0 + row) * 256 + e0 + kg * 4) = ov;
}

// ---- K3: lin GEMM (K=512) + atomic BN stats --------------------------------
// grid 512 = (64 m-tiles) x (8 n-groups); 128 thr (2 waves, all wave-local).
__global__ __launch_bounds__(128, 1) void k_lin(
    const u16* __restrict__ xb, const u16* __restrict__ msg1b,
    const u16* __restrict__ lwp, const float* __restrict__ lb,
    float* __restrict__ msg2, float* __restrict__ gsum, float* __restrict__ gsumsq) {
    __shared__ __align__(16) float T[2][16 * 20];
    const int tid = threadIdx.x, lane = tid & 63, widx = tid >> 6;
    const int row = lane & 15, kg = lane >> 4;
    const int mt = blockIdx.x >> 3, ng = blockIdx.x & 7;
    const int m0 = mt * 16;
    const int n0 = (ng * 2 + widx) * 16;
    const u16* A0 = xb    + (m0 + row) * 256 + kg * 8;
    const u16* A1 = msg1b + (m0 + row) * 256 + kg * 8;
    const u16* B  = lwp + (n0 + row) * 512 + kg * 8;
    f32x4 acc = {0.f,0.f,0.f,0.f};
    #pragma unroll
    for (int k0 = 0; k0 < 512; k0 += 32) {
        short8 av = (k0 < 256) ? ld8(A0 + k0) : ld8(A1 + (k0 - 256));
        acc = __builtin_amdgcn_mfma_f32_16x16x32_bf16(av, ld8(B + k0), acc, 0, 0, 0);
    }
    float bias = lb[n0 + row];
    float v0 = acc[0] + bias, v1 = acc[1] + bias, v2 = acc[2] + bias, v3 = acc[3] + bias;
    float s1 = v0 + v1 + v2 + v3;
    float s2 = v0 * v0 + v1 * v1 + v2 * v2 + v3 * v3;
    s1 += __shfl_xor(s1, 16); s1 += __shfl_xor(s1, 32);
    s2 += __shfl_xor(s2, 16); s2 += __shfl_xor(s2, 32);
    if (lane < 16) {          // lane = n col within tile
        atomicAdd(&gsum[n0 + lane], s1);
        atomicAdd(&gsumsq[n0 + lane], s2);
    }
    float* Tw = &T[widx][0];  // wave-local transpose (no barrier needed)
    Tw[(kg * 4 + 0) * 20 + row] = v0;
    Tw[(kg * 4 + 1) * 20 + row] = v1;
    Tw[(kg * 4 + 2) * 20 + row] = v2;
    Tw[(kg * 4 + 3) * 20 + row] = v3;
    float4 vv = *(float4*)&Tw[row * 20 + kg * 4];
    *(float4*)&msg2[(m0 + row) * 256 + n0 + kg * 4] = vv;
}

// ---- K_fin: final BN + residual + unpack via 32x32 tile transpose ----------
// grid 256 = (32 node-tiles) x (8 f-tiles); 256 thr.
__global__ __launch_bounds__(256) void k_fin(
    const float* __restrict__ x2, const float* __restrict__ msg2,
    const float* __restrict__ gsum, const float* __restrict__ gsumsq,
    const float* __restrict__ bw, const float* __restrict__ bb,
    float* __restrict__ out) {
    __shared__ float Tt[32 * 33];
    __shared__ float scf[32];
    __shared__ float shf[32];
    const int t = threadIdx.x;
    const int nt2 = blockIdx.x >> 3, ft = blockIdx.x & 7;
    const int n0 = nt2 * 32, f0 = ft * 32;
    if (t < 32) {
        float s1 = gsum[f0 + t], s2 = gsumsq[f0 + t];
        float mu  = s1 * (1.f / 1024.f);
        float var = s2 * (1.f / 1024.f) - mu * mu;    // biased, as reference
        float scale = bw[f0 + t] * rsqrtf(var + 1e-5f);
        scf[t] = scale;
        shf[t] = bb[f0 + t] - mu * scale;
    }
    __syncthreads();
    {   // stage BN(x2+msg2) into LDS transposed: Tt[f][node]
        const int nr = t >> 3, f4 = t & 7;
        const int idx = (n0 + nr) * 256 + f0 + f4 * 4;
        float4 v = *(const float4*)&x2[idx];
        float4 m = *(const float4*)&msg2[idx];
        v.x += m.x * scf[f4 * 4 + 0] + shf[f4 * 4 + 0];
        v.y += m.y * scf[f4 * 4 + 1] + shf[f4 * 4 + 1];
        v.z += m.z * scf[f4 * 4 + 2] + shf[f4 * 4 + 2];
        v.w += m.w * scf[f4 * 4 + 3] + shf[f4 * 4 + 3];
        Tt[(f4 * 4 + 0) * 33 + nr] = v.x;
        Tt[(f4 * 4 + 1) * 33 + nr] = v.y;
        Tt[(f4 * 4 + 2) * 33 + nr] = v.z;
        Tt[(f4 * 4 + 3) * 33 + nr] = v.w;
    }
    __syncthreads();
    {   // write out[half][b][f][n] coalesced along n
        const int fr = t >> 3, n4 = t & 7;
        const int b = n0 >> 8, half = (n0 >> 7) & 1, nloc = n0 & 127;
        float4 v;
        v.x = Tt[fr * 33 + n4 * 4 + 0];
        v.y = Tt[fr * 33 + n4 * 4 + 1];
        v.z = Tt[fr * 33 + n4 * 4 + 2];
        v.w = Tt[fr * 33 + n4 * 4 + 3];
        *(float4*)&out[half * 131072 + b * 32768 + (f0 + fr) * 128 + nloc + n4 * 4] = v;
    }
}

// ----------------------------------------------------------------------------
extern "C" void kernel_launch(void* const* d_in, const int* in_sizes, int n_in,
                              void* d_out, int out_size, void* d_ws, size_t ws_size,
                              hipStream_t stream) {
    const float* desc0  = (const float*)d_in[0];
    const float* desc1  = (const float*)d_in[1];
    const float* conv_w = (const float*)d_in[2];
    const float* conv_q = (const float*)d_in[3];
    const float* conv_k = (const float*)d_in[4];
    const float* conv_b = (const float*)d_in[5];
    const float* lin_w  = (const float*)d_in[6];
    const float* lin_b  = (const float*)d_in[7];
    const float* bn_w   = (const float*)d_in[8];
    const float* bn_b   = (const float*)d_in[9];
    float* out = (float*)d_out;

    char* p = (char*)d_ws;
    float* x0     = (float*)p; p += 1048576;
    float* x1     = (float*)p; p += 1048576;
    u16*   xb     = (u16*)p;   p += 524288;
    u16*   Wt     = (u16*)p;   p += 786432;    // [3][2][256e][256f]
    u16*   lwb    = (u16*)p;   p += 786432;
    u16*   Ht     = (u16*)p;   p += 1048576;   // [2][256e][1024node]
    float* qpart  = (float*)p; p += 131072;    // [32][1024]
    float* kpart  = (float*)p; p += 131072;
    u16*   msg1b  = (u16*)p;   p += 524288;
    float* msg2   = (float*)p; p += 1048576;
    float* gsum   = (float*)p; p += 1024;      // [256] atomic accum
    float* gsumsq = (float*)p; p += 1024;

    k_prep<<<1024, 256, 0, stream>>>(desc0, desc1, conv_w, lin_w, x0, xb, Wt, lwb);

    // layer i reads xs[i]; writes xs[i+1] only when do_bn (i>0). Layer 0
    // leaves x unchanged, so layer 1 must read x0 again.
    float* xs[4] = {x0, x0, x1, x0};
    for (int i = 0; i < 3; ++i) {
        const u16*   cwt = Wt + i * 131072;
        const u16*   lwp = lwb + i * 131072;
        const float* cq = conv_q + i * 256;
        const float* ck = conv_k + i * 256;
        const float* cb = conv_b + i * 256;
        const float* lb = lin_b + i * 256;
        const float* bwp = bn_w + (i ? (i - 1) * 256 : 0);   // prev-layer BN
        const float* bbp = bn_b + (i ? (i - 1) * 256 : 0);

        k_hqk<<<512, 256, 0, stream>>>(xs[i], msg2, gsum, gsumsq, bwp, bbp,
                                       cwt, cq, ck, xs[i + 1], xb, Ht,
                                       qpart, kpart, i > 0 ? 1 : 0);
        k_attn<<<256, 256, 0, stream>>>(qpart, kpart, Ht, cb, msg1b, gsum, gsumsq);
        k_lin<<<512, 128, 0, stream>>>(xb, msg1b, lwp, lb, msg2, gsum, gsumsq);
    }

    k_fin<<<256, 256, 0, stream>>>(xs[3], msg2, gsum, gsumsq,
                                   bn_w + 512, bn_b + 512, out);
}